// Round 4
// baseline (666.584 us; speedup 1.0000x reference)
//
#include <hip/hip_runtime.h>
#include <hip/hip_bf16.h>
#include <math.h>

#define N_USERS   100000
#define N_RECIPES 50000
#define NE        600000
#define NL        200000
#define DU        128
#define DR        256
#define H         128
#define OUT_D     64

using half2v = __attribute__((ext_vector_type(2))) _Float16;
using half4v = __attribute__((ext_vector_type(4))) _Float16;
using half8v = __attribute__((ext_vector_type(8))) _Float16;
using f32x4  = __attribute__((ext_vector_type(4))) float;

// ---------------- utility fills ----------------
__global__ void fill_zero_i32(int* __restrict__ p, int n) {
  int i = blockIdx.x * 256 + threadIdx.x;
  if (i < n) p[i] = 0;
}

// ---------------- batched f32 -> fp16 weight conversion ----------------
struct WPack {
  const float* src[10];
  _Float16* dst[10];
  int sz4[10];  // element count / 4
};
__global__ void convert_weights(WPack p) {
  const int m = blockIdx.y;
  const int i = blockIdx.x * 256 + threadIdx.x;
  if (i < p.sz4[m]) {
    float4 v = ((const float4*)p.src[m])[i];
    half4v h;
    h[0] = (_Float16)v.x; h[1] = (_Float16)v.y;
    h[2] = (_Float16)v.z; h[3] = (_Float16)v.w;
    ((half4v*)p.dst[m])[i] = h;
  }
}

// ---------------- degree histogram ----------------
__global__ void hist_kernel(const int* __restrict__ esrc, const int* __restrict__ edst,
                            int* __restrict__ cnt_u, int* __restrict__ cnt_r) {
  int i = blockIdx.x * 256 + threadIdx.x;
  if (i < NE) {
    atomicAdd(&cnt_r[edst[i]], 1);
    atomicAdd(&cnt_u[esrc[i]], 1);
  }
}

// ---------------- 3-phase exclusive scan ----------------
__global__ void scan_phaseA(const int* __restrict__ cnt, int* __restrict__ outx,
                            int* __restrict__ bsum, int n) {
  __shared__ int wsum[4];
  int tid = threadIdx.x;
  int lane = tid & 63, wid = tid >> 6;
  int idx = blockIdx.x * 4096 + tid * 16;
  int v[16];
  int s = 0;
#pragma unroll
  for (int i = 0; i < 16; ++i) {
    int x = (idx + i < n) ? cnt[idx + i] : 0;
    v[i] = s;
    s += x;
  }
  int inc = s;
#pragma unroll
  for (int o = 1; o < 64; o <<= 1) {
    int t = __shfl_up(inc, o, 64);
    if (lane >= o) inc += t;
  }
  if (lane == 63) wsum[wid] = inc;
  __syncthreads();
  int woff = 0;
#pragma unroll
  for (int w = 0; w < 4; ++w)
    if (w < wid) woff += wsum[w];
  int excl = woff + inc - s;
#pragma unroll
  for (int i = 0; i < 16; ++i)
    if (idx + i < n) outx[idx + i] = excl + v[i];
  if (tid == 255) bsum[blockIdx.x] = woff + inc;
}

__global__ void scan_phaseB(int* __restrict__ bsum, int nb, int* __restrict__ off_arr, int n) {
  int lane = threadIdx.x & 63;
  int v = (lane < nb) ? bsum[lane] : 0;
  int inc = v;
#pragma unroll
  for (int o = 1; o < 64; o <<= 1) {
    int t = __shfl_up(inc, o, 64);
    if (lane >= o) inc += t;
  }
  if (lane < nb) bsum[lane] = inc - v;  // exclusive block offset
  if (lane == 63) off_arr[n] = inc;     // grand total (=E)
}

__global__ void scan_phaseC(int* __restrict__ offx, int* __restrict__ cur,
                            const int* __restrict__ bsum, int n) {
  int i = blockIdx.x * 256 + threadIdx.x;
  if (i < n) {
    int v = offx[i] + bsum[i >> 12];
    offx[i] = v;
    cur[i] = v;
  }
}

// ---------------- scatter edge ids into CSR ----------------
__global__ void scatter_kernel(const int* __restrict__ esrc, const int* __restrict__ edst,
                               int* __restrict__ cur_u, int* __restrict__ cur_r,
                               int* __restrict__ eidx_u, int* __restrict__ eidx_r) {
  int i = blockIdx.x * 256 + threadIdx.x;
  if (i < NE) {
    int s = esrc[i], d = edst[i];
    int p = atomicAdd(&cur_r[d], 1);
    eidx_r[p] = s;
    int q = atomicAdd(&cur_u[s], 1);
    eidx_u[q] = d;
  }
}

// ---------------- segment mean (fp16): half-wave per dst node, 4 rows in flight ----------------
__global__ __launch_bounds__(256) void agg_mean_f16(
    const _Float16* __restrict__ feat, const int* __restrict__ offx,
    const int* __restrict__ eidx, _Float16* __restrict__ outm, int n_dst) {
  const int nid = (blockIdx.x * 256 + threadIdx.x) >> 5;
  const int hl = threadIdx.x & 31;
  if (nid >= n_dst) return;
  const int s = offx[nid], e = offx[nid + 1];
  float a0[4] = {0.f, 0.f, 0.f, 0.f};
  float a1[4] = {0.f, 0.f, 0.f, 0.f};
  float a2[4] = {0.f, 0.f, 0.f, 0.f};
  float a3[4] = {0.f, 0.f, 0.f, 0.f};
  int i = s;
  for (; i + 3 < e; i += 4) {
    const int r0 = eidx[i], r1 = eidx[i + 1], r2 = eidx[i + 2], r3 = eidx[i + 3];
    half4v v0 = ((const half4v*)(feat + (size_t)r0 * H))[hl];
    half4v v1 = ((const half4v*)(feat + (size_t)r1 * H))[hl];
    half4v v2 = ((const half4v*)(feat + (size_t)r2 * H))[hl];
    half4v v3 = ((const half4v*)(feat + (size_t)r3 * H))[hl];
#pragma unroll
    for (int t = 0; t < 4; ++t) {
      a0[t] += (float)v0[t];
      a1[t] += (float)v1[t];
      a2[t] += (float)v2[t];
      a3[t] += (float)v3[t];
    }
  }
  for (; i < e; ++i) {
    const int r0 = eidx[i];
    half4v v0 = ((const half4v*)(feat + (size_t)r0 * H))[hl];
#pragma unroll
    for (int t = 0; t < 4; ++t) a0[t] += (float)v0[t];
  }
  const float invc = (e > s) ? 1.f / (float)(e - s) : 0.f;
  half4v o;
#pragma unroll
  for (int t = 0; t < 4; ++t)
    o[t] = (_Float16)((a0[t] + a1[t] + a2[t] + a3[t]) * invc);
  ((half4v*)(outm + (size_t)nid * H))[hl] = o;
}

// ---------------- direct-global fp16 MFMA GEMM (no LDS, no barriers) ----------------
// out[M,BN] = act(A1*W1^T (+ A2*W2^T) + bias). W fp16 [BN,K] row-major.
// 4 waves/block; wave tile 64x64 (4x4 fragments of 16x16x32). Fragments loaded
// straight from global: A rows block-local, W is L1/L2-resident (<=64KB).
template <int BN, int K, bool DUAL, bool RELU, bool A_F32>
__global__ __launch_bounds__(256) void gemm_direct(
    const void* __restrict__ A1v, const _Float16* __restrict__ W1,
    const void* __restrict__ A2v, const _Float16* __restrict__ W2,
    const float* __restrict__ bias, _Float16* __restrict__ outp, int M) {
  constexpr int WN = BN / 64;      // waves along N
  constexpr int BM = (4 / WN) * 64;
  const int lane = threadIdx.x & 63;
  const int wid = threadIdx.x >> 6;
  const int wm = wid / WN;
  const int wn = wid % WN;
  const int m0 = blockIdx.x * BM;
  const int lm = lane & 15;         // row/col within fragment
  const int lkb = (lane >> 4) * 8;  // k offset of this lane's 8 elements

  f32x4 acc[4][4];
  const f32x4 zero4 = {0.f, 0.f, 0.f, 0.f};
#pragma unroll
  for (int i = 0; i < 4; ++i)
#pragma unroll
    for (int j = 0; j < 4; ++j) acc[i][j] = zero4;

  int arow[4];
#pragma unroll
  for (int i = 0; i < 4; ++i) {
    int r = m0 + wm * 64 + i * 16 + lm;
    arow[i] = (r < M) ? r : (M - 1);  // clamp: garbage rows never stored
  }

#pragma unroll
  for (int pass = 0; pass < (DUAL ? 2 : 1); ++pass) {
    const void* Av = pass ? A2v : A1v;
    const _Float16* __restrict__ W = pass ? W2 : W1;
#pragma unroll
    for (int k0 = 0; k0 < K; k0 += 32) {
      half8v af[4], bf[4];
      if constexpr (A_F32) {
        const float* __restrict__ A = (const float*)Av;
#pragma unroll
        for (int i = 0; i < 4; ++i) {
          const float* p = A + (size_t)arow[i] * K + k0 + lkb;
          float4 u = *(const float4*)p;
          float4 v = *(const float4*)(p + 4);
          af[i][0] = (_Float16)u.x; af[i][1] = (_Float16)u.y;
          af[i][2] = (_Float16)u.z; af[i][3] = (_Float16)u.w;
          af[i][4] = (_Float16)v.x; af[i][5] = (_Float16)v.y;
          af[i][6] = (_Float16)v.z; af[i][7] = (_Float16)v.w;
        }
      } else {
        const _Float16* __restrict__ A = (const _Float16*)Av;
#pragma unroll
        for (int i = 0; i < 4; ++i)
          af[i] = *(const half8v*)(A + (size_t)arow[i] * K + k0 + lkb);
      }
#pragma unroll
      for (int j = 0; j < 4; ++j)
        bf[j] = *(const half8v*)(W + (size_t)(wn * 64 + j * 16 + lm) * K + k0 + lkb);
#pragma unroll
      for (int i = 0; i < 4; ++i)
#pragma unroll
        for (int j = 0; j < 4; ++j)
          acc[i][j] = __builtin_amdgcn_mfma_f32_16x16x32_f16(af[i], bf[j], acc[i][j], 0, 0, 0);
    }
  }
  // epilogue: bias (+relu), fp16 store. C layout: col=lane&15, row=(lane>>4)*4+reg
  const int rb = (lane >> 4) * 4;
#pragma unroll
  for (int j = 0; j < 4; ++j) {
    const int col = wn * 64 + j * 16 + lm;
    const float bj = bias[col];
#pragma unroll
    for (int i = 0; i < 4; ++i) {
#pragma unroll
      for (int r = 0; r < 4; ++r) {
        const int grow = m0 + wm * 64 + i * 16 + rb + r;
        if (grow < M) {
          float v = acc[i][j][r] + bj;
          if (RELU) v = fmaxf(v, 0.f);
          outp[(size_t)grow * BN + col] = (_Float16)v;
        }
      }
    }
  }
}

// ---------------- decoder: one wave per label pair (fp16 inputs) ----------------
__global__ __launch_bounds__(256) void decoder_f16(
    const _Float16* __restrict__ zu, const _Float16* __restrict__ zr,
    const int* __restrict__ ls, const int* __restrict__ ld,
    float* __restrict__ outp) {
  const int w = (blockIdx.x * 256 + threadIdx.x) >> 6;
  if (w >= NL) return;
  const int lane = threadIdx.x & 63;
  const int hl = lane & 31;
  const _Float16* src = (lane >= 32) ? (zr + (size_t)ld[w] * OUT_D)
                                     : (zu + (size_t)ls[w] * OUT_D);
  half2v v = ((const half2v*)src)[hl];
  float x0 = (float)v[0], x1 = (float)v[1];
  float y0 = __shfl_xor(x0, 32, 64);
  float y1 = __shfl_xor(x1, 32, 64);
  float nx = x0 * x0 + x1 * x1;
  float ny = y0 * y0 + y1 * y1;
  float ab = x0 * y0 + x1 * y1;
#pragma unroll
  for (int o = 16; o > 0; o >>= 1) {
    nx += __shfl_xor(nx, o, 64);
    ny += __shfl_xor(ny, o, 64);
    ab += __shfl_xor(ab, o, 64);
  }
  if (lane == 0) {
    float denom = fmaxf(sqrtf(nx), 1e-12f) * fmaxf(sqrtf(ny), 1e-12f);
    outp[w] = ab / denom;
  }
}

extern "C" void kernel_launch(void* const* d_in, const int* in_sizes, int n_in,
                              void* d_out, int out_size, void* d_ws, size_t ws_size,
                              hipStream_t stream) {
  (void)in_sizes; (void)n_in; (void)out_size; (void)ws_size;
  const float* x_user   = (const float*)d_in[0];
  const float* x_recipe = (const float*)d_in[1];
  const int* edge_src   = (const int*)d_in[2];
  const int* edge_dst   = (const int*)d_in[3];
  const int* lbl_src    = (const int*)d_in[4];
  const int* lbl_dst    = (const int*)d_in[5];
  const float* Wu       = (const float*)d_in[6];
  const float* bu       = (const float*)d_in[7];
  const float* Wrec     = (const float*)d_in[8];
  const float* brec     = (const float*)d_in[9];
  const float* c1_ur_Wl = (const float*)d_in[10];
  const float* c1_ur_bl = (const float*)d_in[11];
  const float* c1_ur_Wr = (const float*)d_in[12];
  const float* c1_ru_Wl = (const float*)d_in[13];
  const float* c1_ru_bl = (const float*)d_in[14];
  const float* c1_ru_Wr = (const float*)d_in[15];
  const float* c2_ur_Wl = (const float*)d_in[16];
  const float* c2_ur_bl = (const float*)d_in[17];
  const float* c2_ur_Wr = (const float*)d_in[18];
  const float* c2_ru_Wl = (const float*)d_in[19];
  const float* c2_ru_bl = (const float*)d_in[20];
  const float* c2_ru_Wr = (const float*)d_in[21];
  float* out = (float*)d_out;

  char* ws = (char*)d_ws;
  size_t off = 0;
  auto take = [&](size_t bytes) -> void* {
    void* p = ws + off;
    off = (off + bytes + 255) & ~(size_t)255;
    return p;
  };
  _Float16* hu   = (_Float16*)take((size_t)N_USERS * H * 2);    // 25.6 MB
  _Float16* hr   = (_Float16*)take((size_t)N_RECIPES * H * 2);  // 12.8 MB
  _Float16* mean = (_Float16*)take((size_t)N_USERS * H * 2);    // 25.6 MB (reused 4x)
  _Float16* r1   = (_Float16*)take((size_t)N_RECIPES * H * 2);
  _Float16* u1   = (_Float16*)take((size_t)N_USERS * H * 2);
  int* cnt_all = (int*)take((size_t)(N_RECIPES + N_USERS) * 4);
  int* cnt_r = cnt_all;
  int* cnt_u = cnt_all + N_RECIPES;
  int* off_r  = (int*)take((size_t)(N_RECIPES + 1) * 4);
  int* cur_r  = (int*)take((size_t)N_RECIPES * 4);
  int* off_u  = (int*)take((size_t)(N_USERS + 1) * 4);
  int* cur_u  = (int*)take((size_t)N_USERS * 4);
  int* eidx_r = (int*)take((size_t)NE * 4);
  int* eidx_u = (int*)take((size_t)NE * 4);
  int* bsum_r = (int*)take(64 * 4);
  int* bsum_u = (int*)take(64 * 4);
  // fp16 weights (pre-converted once per call)
  _Float16* Wu_h    = (_Float16*)take(H * DU * 2);
  _Float16* Wrec_h  = (_Float16*)take(H * DR * 2);
  _Float16* c1urWl_h = (_Float16*)take(H * H * 2);
  _Float16* c1urWr_h = (_Float16*)take(H * H * 2);
  _Float16* c1ruWl_h = (_Float16*)take(H * H * 2);
  _Float16* c1ruWr_h = (_Float16*)take(H * H * 2);
  _Float16* c2urWl_h = (_Float16*)take(OUT_D * H * 2);
  _Float16* c2urWr_h = (_Float16*)take(OUT_D * H * 2);
  _Float16* c2ruWl_h = (_Float16*)take(OUT_D * H * 2);
  _Float16* c2ruWr_h = (_Float16*)take(OUT_D * H * 2);
  // final embeddings alias buffers dead by the time they're written
  _Float16* zr = hr;  // hr last read in agg for u1; zr written after
  _Float16* zu = hu;  // hu last read in conv1-u GEMM; zu written after

  // ---- weight conversion (single batched launch)
  WPack wp;
  wp.src[0] = Wu;       wp.dst[0] = Wu_h;     wp.sz4[0] = H * DU / 4;
  wp.src[1] = Wrec;     wp.dst[1] = Wrec_h;   wp.sz4[1] = H * DR / 4;
  wp.src[2] = c1_ur_Wl; wp.dst[2] = c1urWl_h; wp.sz4[2] = H * H / 4;
  wp.src[3] = c1_ur_Wr; wp.dst[3] = c1urWr_h; wp.sz4[3] = H * H / 4;
  wp.src[4] = c1_ru_Wl; wp.dst[4] = c1ruWl_h; wp.sz4[4] = H * H / 4;
  wp.src[5] = c1_ru_Wr; wp.dst[5] = c1ruWr_h; wp.sz4[5] = H * H / 4;
  wp.src[6] = c2_ur_Wl; wp.dst[6] = c2urWl_h; wp.sz4[6] = OUT_D * H / 4;
  wp.src[7] = c2_ur_Wr; wp.dst[7] = c2urWr_h; wp.sz4[7] = OUT_D * H / 4;
  wp.src[8] = c2_ru_Wl; wp.dst[8] = c2ruWl_h; wp.sz4[8] = OUT_D * H / 4;
  wp.src[9] = c2_ru_Wr; wp.dst[9] = c2ruWr_h; wp.sz4[9] = OUT_D * H / 4;
  convert_weights<<<dim3(32, 10), 256, 0, stream>>>(wp);

  // ---- CSR build (both directions)
  fill_zero_i32<<<(N_RECIPES + N_USERS + 255) / 256, 256, 0, stream>>>(cnt_all,
                                                                       N_RECIPES + N_USERS);
  hist_kernel<<<(NE + 255) / 256, 256, 0, stream>>>(edge_src, edge_dst, cnt_u, cnt_r);
  int nbR = (N_RECIPES + 4095) / 4096;  // 13
  int nbU = (N_USERS + 4095) / 4096;    // 25
  scan_phaseA<<<nbR, 256, 0, stream>>>(cnt_r, off_r, bsum_r, N_RECIPES);
  scan_phaseB<<<1, 64, 0, stream>>>(bsum_r, nbR, off_r, N_RECIPES);
  scan_phaseC<<<(N_RECIPES + 255) / 256, 256, 0, stream>>>(off_r, cur_r, bsum_r, N_RECIPES);
  scan_phaseA<<<nbU, 256, 0, stream>>>(cnt_u, off_u, bsum_u, N_USERS);
  scan_phaseB<<<1, 64, 0, stream>>>(bsum_u, nbU, off_u, N_USERS);
  scan_phaseC<<<(N_USERS + 255) / 256, 256, 0, stream>>>(off_u, cur_u, bsum_u, N_USERS);
  scatter_kernel<<<(NE + 255) / 256, 256, 0, stream>>>(edge_src, edge_dst, cur_u, cur_r,
                                                       eidx_u, eidx_r);

  // ---- input projections (f32 A converted in-register)
  gemm_direct<128, DU, false, false, true><<<(N_USERS + 127) / 128, 256, 0, stream>>>(
      x_user, Wu_h, nullptr, nullptr, bu, hu, N_USERS);
  gemm_direct<128, DR, false, false, true><<<(N_RECIPES + 127) / 128, 256, 0, stream>>>(
      x_recipe, Wrec_h, nullptr, nullptr, brec, hr, N_RECIPES);

  // ---- conv1
  agg_mean_f16<<<(N_RECIPES * 32 + 255) / 256, 256, 0, stream>>>(hu, off_r, eidx_r, mean,
                                                                 N_RECIPES);
  gemm_direct<128, H, true, true, false><<<(N_RECIPES + 127) / 128, 256, 0, stream>>>(
      mean, c1urWl_h, hr, c1urWr_h, c1_ur_bl, r1, N_RECIPES);
  agg_mean_f16<<<(N_USERS * 32 + 255) / 256, 256, 0, stream>>>(hr, off_u, eidx_u, mean,
                                                               N_USERS);
  gemm_direct<128, H, true, true, false><<<(N_USERS + 127) / 128, 256, 0, stream>>>(
      mean, c1ruWl_h, hu, c1ruWr_h, c1_ru_bl, u1, N_USERS);

  // ---- conv2 (BN=64: BM=256, 4x1 waves)
  agg_mean_f16<<<(N_RECIPES * 32 + 255) / 256, 256, 0, stream>>>(u1, off_r, eidx_r, mean,
                                                                 N_RECIPES);
  gemm_direct<64, H, true, false, false><<<(N_RECIPES + 255) / 256, 256, 0, stream>>>(
      mean, c2urWl_h, r1, c2urWr_h, c2_ur_bl, zr, N_RECIPES);
  agg_mean_f16<<<(N_USERS * 32 + 255) / 256, 256, 0, stream>>>(r1, off_u, eidx_u, mean,
                                                               N_USERS);
  gemm_direct<64, H, true, false, false><<<(N_USERS + 255) / 256, 256, 0, stream>>>(
      mean, c2ruWl_h, u1, c2ruWr_h, c2_ru_bl, zu, N_USERS);

  // ---- decoder
  decoder_f16<<<((size_t)NL * 64 + 255) / 256, 256, 0, stream>>>(zu, zr, lbl_src, lbl_dst, out);
}